// Round 8
// baseline (878.529 us; speedup 1.0000x reference)
//
#include <hip/hip_runtime.h>

#define NB   16
#define NN   2048
#define NPTS (NB * NN)
#define KNB  6

// constant-address-space pointer: uniform loads compile to s_load (scalar pipe)
typedef const __attribute__((address_space(4))) float cfloat;

// ---------------- squared-norm kernel ----------------
template<int C>
__global__ void sq_kernel(const float* __restrict__ x, float* __restrict__ sq) {
    int i = blockIdx.x * blockDim.x + threadIdx.x;
    if (i >= NPTS) return;
    const float4* r = (const float4*)(x + (size_t)i * C);
    float s = 0.f;
#pragma unroll
    for (int c = 0; c < C / 4; ++c) {
        float4 f = r[c];
        s += f.x * f.x + f.y * f.y + f.z * f.z + f.w * f.w;
    }
    sq[i] = s;
}

// ---------------- weight prep: transpose the three W1s ----------------
__global__ void prep_w(const float* __restrict__ W10, const float* __restrict__ W11,
                       const float* __restrict__ W12,
                       float* __restrict__ T0, float* __restrict__ T1,
                       float* __restrict__ T2) {
    int t = blockIdx.x * 256 + threadIdx.x;
    if (t < 4096) { int o = t >> 6, c = t & 63;  T0[o * 64 + c]  = W10[c * 64 + o]; }
    if (t < 4096) { int o = t >> 7, c = t & 127; T1[o * 128 + c] = W11[c * 32 + o]; }
    if (t < 4096) { int o = t >> 6, c = t & 63;  T2[o * 64 + c]  = W12[c * 64 + o]; }
}

// branchless stable insert of (s, j) into ascending 6-list (round-4 validated)
__device__ __forceinline__ void insert6(float s, int j, float* dl, int* il) {
    float cd = s; int ci = j;
#pragma unroll
    for (int k = 0; k < 6; ++k) {
        const float od = dl[k]; const int oi = il[k];
        const bool c = cd < od;          // strict: existing wins ties -> stable
        dl[k] = c ? cd : od;
        il[k] = c ? ci : oi;
        cd = c ? od : cd;
        ci = c ? oi : ci;
    }
}

// ---------------- kNN scan kernel ----------------
// lane = query (Q rows resident in VGPRs, PINNED via empty asm so the
// allocator cannot demote them — rounds 5-7 failure mode). Candidate rows +
// sq stream via address_space(4) uniform loads -> s_load (scalar pipe,
// zero LDS, zero VMEM in the hot loop). Branchless insert6.
// grid (NN/(256*Q), NB, SPLN); block = 4 waves, same candidate range z.
template<int C, int Q, int SPLN>
__global__ __launch_bounds__(256)
void knn_scan(const float* __restrict__ x, const float* __restrict__ sq,
              unsigned long long* __restrict__ plist) {
    constexpr int RANGE = NN / SPLN;
    const int lane = threadIdx.x & 63;
    const int w    = threadIdx.x >> 6;
    const int b    = blockIdx.y;
    const int z    = blockIdx.z;
    const int base = b * NN;
    const int cbase = z * RANGE;
    const int q0 = blockIdx.x * (256 * Q) + w * (64 * Q) + lane;  // batch-local

    // Q query rows per lane, in registers
    float qr[Q][C];
    int   qidx[Q];
#pragma unroll
    for (int qq = 0; qq < Q; ++qq) {
        qidx[qq] = q0 + 64 * qq;
        const float* qp = x + (size_t)(base + qidx[qq]) * C;
#pragma unroll
        for (int c = 0; c < C; c += 4) {
            float4 f = *(const float4*)(qp + c);
            qr[qq][c] = f.x; qr[qq][c + 1] = f.y;
            qr[qq][c + 2] = f.z; qr[qq][c + 3] = f.w;
        }
    }
    // PIN: force each query element into a live VGPR the optimizer can't
    // rematerialize or sink back to memory.
#pragma unroll
    for (int qq = 0; qq < Q; ++qq)
#pragma unroll
        for (int c = 0; c < C; ++c)
            asm volatile("" : "+v"(qr[qq][c]));

    float dl[Q][6]; int il[Q][6];
#pragma unroll
    for (int qq = 0; qq < Q; ++qq)
#pragma unroll
        for (int k = 0; k < 6; ++k) { dl[qq][k] = 1e30f; il[qq][k] = 0; }

    // uniform candidate stream through the scalar pipe
    cfloat* rp  = (cfloat*)(uintptr_t)(x + (size_t)(base + cbase) * C);
    cfloat* sqp = (cfloat*)(uintptr_t)(sq + base + cbase);

    for (int j = 0; j < RANGE; ++j) {
        cfloat* row = rp + (size_t)j * C;                // uniform -> s_load
        float a[Q][4];
#pragma unroll
        for (int qq = 0; qq < Q; ++qq) {
            a[qq][0] = 0.f; a[qq][1] = 0.f; a[qq][2] = 0.f; a[qq][3] = 0.f;
        }
#pragma unroll
        for (int c = 0; c < C; ++c) {
            const float rv = row[c];                     // SGPR operand
#pragma unroll
            for (int qq = 0; qq < Q; ++qq)
                a[qq][c & 3] = fmaf(rv, qr[qq][c], a[qq][c & 3]);
        }
        const int jj = cbase + j;
        const float sj = sqp[j];
#pragma unroll
        for (int qq = 0; qq < Q; ++qq) {
            float s = fmaf(-2.f, (a[qq][0] + a[qq][1]) + (a[qq][2] + a[qq][3]), sj);
            s = (jj == qidx[qq]) ? 1e30f : s;            // self-exclusion
            insert6(s, jj, dl[qq], il[qq]);
        }
    }

    // packed sortable keys: (flip(score) << 11) | cand_idx (ascending)
#pragma unroll
    for (int qq = 0; qq < Q; ++qq) {
        unsigned long long* o = plist + ((size_t)z * NPTS + (base + qidx[qq])) * KNB;
#pragma unroll
        for (int k = 0; k < 6; ++k) {
            unsigned u = __float_as_uint(dl[qq][k]);
            u ^= (u & 0x80000000u) ? 0xFFFFFFFFu : 0x80000000u;
            o[k] = ((unsigned long long)u << 11) | (unsigned)(il[qq][k] & 2047);
        }
    }
}

// ---------------- kNN merge kernel ----------------
// thread = one query; merge SPLN sorted 6-lists -> top-6 global indices.
template<int SPLN>
__global__ __launch_bounds__(256) void knn_merge(const unsigned long long* __restrict__ plist,
                                                 int* __restrict__ nbr) {
    const int q = blockIdx.x * 256 + threadIdx.x;
    if (q >= NPTS) return;
    unsigned long long best[6];
#pragma unroll
    for (int k = 0; k < 6; ++k) best[k] = ~0ull;
    for (int cg = 0; cg < SPLN; ++cg) {
        const unsigned long long* p = plist + ((size_t)cg * NPTS + q) * KNB;
        for (int e = 0; e < 6; ++e) {
            unsigned long long v = p[e];
            if (v >= best[5]) break;   // sublist ascending
            best[5] = v;
#pragma unroll
            for (int k = 4; k >= 0; --k) {
                if (best[k + 1] < best[k]) {
                    unsigned long long t = best[k]; best[k] = best[k + 1]; best[k + 1] = t;
                }
            }
        }
    }
    const int b = q >> 11;
#pragma unroll
    for (int k = 0; k < 6; ++k)
        nbr[q * KNB + k] = (b << 11) | (int)(best[k] & 2047ull);
}

// ---------------- edge MLP kernel ----------------
// block = 384 thr = 6 waves; lane = point; wave = neighbor. Weight streams
// via address_space(4) uniform loads (scalar pipe); 6->1 max via LDS tree.
template<int CIN, int COUT, bool RESID, int MINW>
__global__ __launch_bounds__(384, MINW)
void mlp_kernel(const float* __restrict__ xin, const int* __restrict__ nbr,
                const float* __restrict__ W1T, const float* __restrict__ b1,
                const float* __restrict__ W2,  const float* __restrict__ b2,
                const float* __restrict__ resid, float* __restrict__ out) {
    constexpr int RS = COUT + 4;
    __shared__ float Buf[3][64][RS];

    const int lane = threadIdx.x & 63;
    const int w    = __builtin_amdgcn_readfirstlane(threadIdx.x >> 6);  // 0..5
    const int i    = blockIdx.x * 64 + lane;

    float xi[CIN], xd[CIN];
    {
        const float* xp = xin + (size_t)i * CIN;
#pragma unroll
        for (int c = 0; c < CIN; c += 4) {
            float4 f = *(const float4*)(xp + c);
            xi[c] = f.x; xi[c + 1] = f.y; xi[c + 2] = f.z; xi[c + 3] = f.w;
        }
        const int j = nbr[i * KNB + w];
        const float* jp = xin + (size_t)j * CIN;
#pragma unroll
        for (int c = 0; c < CIN; c += 4) {
            float4 f = *(const float4*)(jp + c);
            xd[c]     = f.x - xi[c];     xd[c + 1] = f.y - xi[c + 1];
            xd[c + 2] = f.z - xi[c + 2]; xd[c + 3] = f.w - xi[c + 3];
        }
    }

    float uacc[COUT];
#pragma unroll
    for (int o = 0; o < COUT; ++o) uacc[o] = 0.f;

    cfloat* W1c = (cfloat*)(uintptr_t)W1T;
    cfloat* b1c = (cfloat*)(uintptr_t)b1;
    cfloat* W2c = (cfloat*)(uintptr_t)W2;

    for (int op = 0; op < COUT; ++op) {
        cfloat* w1r = W1c + (size_t)op * (2 * CIN);
        float h0 = 0.f, h1 = 0.f, h2 = 0.f, h3 = 0.f;
#pragma unroll
        for (int c = 0; c < CIN; c += 4) {
            h0 = fmaf(w1r[c],     xi[c],     h0);
            h1 = fmaf(w1r[c + 1], xi[c + 1], h1);
            h2 = fmaf(w1r[c + 2], xi[c + 2], h2);
            h3 = fmaf(w1r[c + 3], xi[c + 3], h3);
        }
#pragma unroll
        for (int c = 0; c < CIN; c += 4) {
            h0 = fmaf(w1r[CIN + c],     xd[c],     h0);
            h1 = fmaf(w1r[CIN + c + 1], xd[c + 1], h1);
            h2 = fmaf(w1r[CIN + c + 2], xd[c + 2], h2);
            h3 = fmaf(w1r[CIN + c + 3], xd[c + 3], h3);
        }
        const float h = fmaxf((h0 + h1) + (h2 + h3) + b1c[op], 0.f);
        cfloat* w2r = W2c + (size_t)op * COUT;
#pragma unroll
        for (int o = 0; o < COUT; ++o)
            uacc[o] = fmaf(w2r[o], h, uacc[o]);
    }

    if (w >= 3) {
#pragma unroll
        for (int o = 0; o < COUT; ++o) Buf[w - 3][lane][o] = uacc[o];
    }
    __syncthreads();
    if (w < 3) {
#pragma unroll
        for (int o = 0; o < COUT; ++o) uacc[o] = fmaxf(uacc[o], Buf[w][lane][o]);
    }
    __syncthreads();
    if (w == 1 || w == 2) {
#pragma unroll
        for (int o = 0; o < COUT; ++o) Buf[w][lane][o] = uacc[o];
    }
    __syncthreads();
    if (w == 0) {
        float* po = out + (size_t)i * COUT;
#pragma unroll
        for (int o = 0; o < COUT; ++o) {
            float v = fmaxf(uacc[o], fmaxf(Buf[1][lane][o], Buf[2][lane][o])) + b2[o];
            if (RESID) v += resid[(size_t)i * COUT + o];
            po[o] = fmaxf(v, 0.f);
        }
    }
}

extern "C" void kernel_launch(void* const* d_in, const int* in_sizes, int n_in,
                              void* d_out, int out_size, void* d_ws, size_t ws_size,
                              hipStream_t stream) {
    const float* x    = (const float*)d_in[0];
    const float* W1_0 = (const float*)d_in[2];
    const float* b1_0 = (const float*)d_in[3];
    const float* W2_0 = (const float*)d_in[4];
    const float* b2_0 = (const float*)d_in[5];
    const float* W1_1 = (const float*)d_in[6];
    const float* b1_1 = (const float*)d_in[7];
    const float* W2_1 = (const float*)d_in[8];
    const float* b2_1 = (const float*)d_in[9];
    const float* W1_2 = (const float*)d_in[10];
    const float* b1_2 = (const float*)d_in[11];
    const float* W2_2 = (const float*)d_in[12];
    const float* b2_2 = (const float*)d_in[13];
    float* outp = (float*)d_out;

    // workspace layout (plist first for 8B alignment); max SPLN = 16
    unsigned long long* plist = (unsigned long long*)d_ws;        // 16*NPTS*6
    float* x0  = (float*)(plist + (size_t)16 * NPTS * KNB);       // 32768 x 64
    float* x1  = x0 + (size_t)NPTS * 64;                          // 32768 x 32
    float* sqb = x1 + (size_t)NPTS * 32;                          // 32768
    float* T0  = sqb + NPTS;                                      // 64 x 64
    float* T1  = T0 + 4096;                                       // 32 x 128
    float* T2  = T1 + 4096;                                       // 64 x 64
    int*   nbr = (int*)(T2 + 4096);                               // 32768 x 6

    // C=32: Q=2, SPL=16 -> grid (4,16,16) = 1024 blocks = 4096 waves (4/SIMD)
    // C=64: Q=1, SPL=8  -> grid (8,16,8)  = 1024 blocks = 4096 waves (4/SIMD)
    const dim3 g32(NN / 512, NB, 16);
    const dim3 g64(NN / 256, NB, 8);
    const int  sgrid = NPTS / 256;
    const int  pgrid = NPTS / 64;

    prep_w<<<16, 256, 0, stream>>>(W1_0, W1_1, W1_2, T0, T1, T2);

    // ---- layer 0: x (32) -> x0 (64), relu ----
    sq_kernel<32><<<sgrid, 256, 0, stream>>>(x, sqb);
    knn_scan<32, 2, 16><<<g32, 256, 0, stream>>>(x, sqb, plist);
    knn_merge<16><<<sgrid, 256, 0, stream>>>(plist, nbr);
    mlp_kernel<32, 64, false, 3><<<pgrid, 384, 0, stream>>>(x, nbr, T0, b1_0, W2_0, b2_0, nullptr, x0);

    // ---- layer 1: x0 (64) -> x1 (32), relu ----
    sq_kernel<64><<<sgrid, 256, 0, stream>>>(x0, sqb);
    knn_scan<64, 1, 8><<<g64, 256, 0, stream>>>(x0, sqb, plist);
    knn_merge<8><<<sgrid, 256, 0, stream>>>(plist, nbr);
    mlp_kernel<64, 32, false, 2><<<pgrid, 384, 0, stream>>>(x0, nbr, T1, b1_1, W2_1, b2_1, nullptr, x1);

    // ---- layer 2: x1 (32) -> out (64), +x0 residual, relu ----
    sq_kernel<32><<<sgrid, 256, 0, stream>>>(x1, sqb);
    knn_scan<32, 2, 16><<<g32, 256, 0, stream>>>(x1, sqb, plist);
    knn_merge<16><<<sgrid, 256, 0, stream>>>(plist, nbr);
    mlp_kernel<32, 64, true, 3><<<pgrid, 384, 0, stream>>>(x1, nbr, T2, b1_2, W2_2, b2_2, x0, outp);
}

// Round 9
// 827.976 us; speedup vs baseline: 1.0611x; 1.0611x over previous
//
#include <hip/hip_runtime.h>

#define NB   16
#define NN   2048
#define NPTS (NB * NN)
#define KNB  6

// constant-address-space pointer: uniform loads compile to s_load (scalar pipe)
typedef const __attribute__((address_space(4))) float cfloat;

// ---------------- squared-norm kernel ----------------
template<int C>
__global__ void sq_kernel(const float* __restrict__ x, float* __restrict__ sq) {
    int i = blockIdx.x * blockDim.x + threadIdx.x;
    if (i >= NPTS) return;
    const float4* r = (const float4*)(x + (size_t)i * C);
    float s = 0.f;
#pragma unroll
    for (int c = 0; c < C / 4; ++c) {
        float4 f = r[c];
        s += f.x * f.x + f.y * f.y + f.z * f.z + f.w * f.w;
    }
    sq[i] = s;
}

// ---------------- weight prep: transpose the three W1s ----------------
__global__ void prep_w(const float* __restrict__ W10, const float* __restrict__ W11,
                       const float* __restrict__ W12,
                       float* __restrict__ T0, float* __restrict__ T1,
                       float* __restrict__ T2) {
    int t = blockIdx.x * 256 + threadIdx.x;
    if (t < 4096) { int o = t >> 6, c = t & 63;  T0[o * 64 + c]  = W10[c * 64 + o]; }
    if (t < 4096) { int o = t >> 7, c = t & 127; T1[o * 128 + c] = W11[c * 32 + o]; }
    if (t < 4096) { int o = t >> 6, c = t & 63;  T2[o * 64 + c]  = W12[c * 64 + o]; }
}

// branchless stable insert of (s, j) into ascending 6-list (round-4 validated)
__device__ __forceinline__ void insert6(float s, int j, float* dl, int* il) {
    float cd = s; int ci = j;
#pragma unroll
    for (int k = 0; k < 6; ++k) {
        const float od = dl[k]; const int oi = il[k];
        const bool c = cd < od;          // strict: existing wins ties -> stable
        dl[k] = c ? cd : od;
        il[k] = c ? ci : oi;
        cd = c ? od : cd;
        ci = c ? oi : ci;
    }
}

// ---------------- kNN scan kernel ----------------
// lane = query. Query rows are loaded then passed through an IDENTITY
// ds_bpermute: a cross-lane op is not rematerializable, so the values are
// forced to stay VGPR-resident (defeats the reload-remat that inflated
// rounds 3-8 ~3x). Candidate rows + sq stream via address_space(4) uniform
// loads -> s_load (scalar pipe; SGPR operand feeds v_fmac directly).
// 1-D grid, z = bid % SPLN -> all blocks scanning range z share an XCD
// (bid%8), so the candidate window is fetched into each L2 once.
template<int C, int Q, int SPLN>
__global__ __launch_bounds__(256, 2)
void knn_scan(const float* __restrict__ x, const float* __restrict__ sq,
              unsigned long long* __restrict__ plist) {
    constexpr int RANGE = NN / SPLN;
    constexpr int NQG   = NN / (256 * Q);
    const int bid  = blockIdx.x;
    const int z    = bid & (SPLN - 1);           // fastest -> same z same XCD
    const int qg   = (bid / SPLN) & (NQG - 1);
    const int b    = bid / (SPLN * NQG);
    const int lane = threadIdx.x & 63;
    const int w    = threadIdx.x >> 6;
    const int base = b * NN;
    const int cbase = z * RANGE;
    const int q0 = qg * (256 * Q) + w * (64 * Q) + lane;   // batch-local
    const int lane4 = lane << 2;

    // Q query rows per lane, in registers
    float qr[Q][C];
    int   qidx[Q];
#pragma unroll
    for (int qq = 0; qq < Q; ++qq) {
        qidx[qq] = q0 + 64 * qq;
        const float* qp = x + (size_t)(base + qidx[qq]) * C;
#pragma unroll
        for (int c = 0; c < C; c += 4) {
            float4 f = *(const float4*)(qp + c);
            qr[qq][c] = f.x; qr[qq][c + 1] = f.y;
            qr[qq][c + 2] = f.z; qr[qq][c + 3] = f.w;
        }
    }
    // PIN: identity cross-lane permute -> non-rematerializable SSA values.
#pragma unroll
    for (int qq = 0; qq < Q; ++qq)
#pragma unroll
        for (int c = 0; c < C; ++c)
            qr[qq][c] = __int_as_float(
                __builtin_amdgcn_ds_bpermute(lane4, __float_as_int(qr[qq][c])));

    float dl[Q][6]; int il[Q][6];
#pragma unroll
    for (int qq = 0; qq < Q; ++qq)
#pragma unroll
        for (int k = 0; k < 6; ++k) { dl[qq][k] = 1e30f; il[qq][k] = 0; }

    // uniform candidate stream through the scalar pipe
    cfloat* rp  = (cfloat*)(uintptr_t)(x + (size_t)(base + cbase) * C);
    cfloat* sqp = (cfloat*)(uintptr_t)(sq + base + cbase);

    for (int j = 0; j < RANGE; ++j) {
        cfloat* row = rp + (size_t)j * C;                // uniform -> s_load
        float a[Q][4];
#pragma unroll
        for (int qq = 0; qq < Q; ++qq) {
            a[qq][0] = 0.f; a[qq][1] = 0.f; a[qq][2] = 0.f; a[qq][3] = 0.f;
        }
#pragma unroll
        for (int c = 0; c < C; ++c) {
            const float rv = row[c];                     // SGPR operand
#pragma unroll
            for (int qq = 0; qq < Q; ++qq)
                a[qq][c & 3] = fmaf(rv, qr[qq][c], a[qq][c & 3]);
        }
        const int jj = cbase + j;
        const float sj = sqp[j];
#pragma unroll
        for (int qq = 0; qq < Q; ++qq) {
            float s = fmaf(-2.f, (a[qq][0] + a[qq][1]) + (a[qq][2] + a[qq][3]), sj);
            s = (jj == qidx[qq]) ? 1e30f : s;            // self-exclusion
            insert6(s, jj, dl[qq], il[qq]);
        }
    }

    // packed sortable keys: (flip(score) << 11) | cand_idx (ascending)
#pragma unroll
    for (int qq = 0; qq < Q; ++qq) {
        unsigned long long* o = plist + ((size_t)z * NPTS + (base + qidx[qq])) * KNB;
#pragma unroll
        for (int k = 0; k < 6; ++k) {
            unsigned u = __float_as_uint(dl[qq][k]);
            u ^= (u & 0x80000000u) ? 0xFFFFFFFFu : 0x80000000u;
            o[k] = ((unsigned long long)u << 11) | (unsigned)(il[qq][k] & 2047);
        }
    }
}

// ---------------- kNN merge kernel ----------------
// thread = one query; merge SPLN sorted 6-lists -> top-6 global indices.
template<int SPLN>
__global__ __launch_bounds__(256) void knn_merge(const unsigned long long* __restrict__ plist,
                                                 int* __restrict__ nbr) {
    const int q = blockIdx.x * 256 + threadIdx.x;
    if (q >= NPTS) return;
    unsigned long long best[6];
#pragma unroll
    for (int k = 0; k < 6; ++k) best[k] = ~0ull;
    for (int cg = 0; cg < SPLN; ++cg) {
        const unsigned long long* p = plist + ((size_t)cg * NPTS + q) * KNB;
        for (int e = 0; e < 6; ++e) {
            unsigned long long v = p[e];
            if (v >= best[5]) break;   // sublist ascending
            best[5] = v;
#pragma unroll
            for (int k = 4; k >= 0; --k) {
                if (best[k + 1] < best[k]) {
                    unsigned long long t = best[k]; best[k] = best[k + 1]; best[k + 1] = t;
                }
            }
        }
    }
    const int b = q >> 11;
#pragma unroll
    for (int k = 0; k < 6; ++k)
        nbr[q * KNB + k] = (b << 11) | (int)(best[k] & 2047ull);
}

// ---------------- edge MLP kernel ----------------
// block = 384 thr = 6 waves; lane = point; wave = neighbor. Weight streams
// via address_space(4) uniform loads (scalar pipe); 6->1 max via LDS tree.
template<int CIN, int COUT, bool RESID, int MINW>
__global__ __launch_bounds__(384, MINW)
void mlp_kernel(const float* __restrict__ xin, const int* __restrict__ nbr,
                const float* __restrict__ W1T, const float* __restrict__ b1,
                const float* __restrict__ W2,  const float* __restrict__ b2,
                const float* __restrict__ resid, float* __restrict__ out) {
    constexpr int RS = COUT + 4;
    __shared__ float Buf[3][64][RS];

    const int lane = threadIdx.x & 63;
    const int w    = __builtin_amdgcn_readfirstlane(threadIdx.x >> 6);  // 0..5
    const int i    = blockIdx.x * 64 + lane;

    float xi[CIN], xd[CIN];
    {
        const float* xp = xin + (size_t)i * CIN;
#pragma unroll
        for (int c = 0; c < CIN; c += 4) {
            float4 f = *(const float4*)(xp + c);
            xi[c] = f.x; xi[c + 1] = f.y; xi[c + 2] = f.z; xi[c + 3] = f.w;
        }
        const int j = nbr[i * KNB + w];
        const float* jp = xin + (size_t)j * CIN;
#pragma unroll
        for (int c = 0; c < CIN; c += 4) {
            float4 f = *(const float4*)(jp + c);
            xd[c]     = f.x - xi[c];     xd[c + 1] = f.y - xi[c + 1];
            xd[c + 2] = f.z - xi[c + 2]; xd[c + 3] = f.w - xi[c + 3];
        }
    }

    float uacc[COUT];
#pragma unroll
    for (int o = 0; o < COUT; ++o) uacc[o] = 0.f;

    cfloat* W1c = (cfloat*)(uintptr_t)W1T;
    cfloat* b1c = (cfloat*)(uintptr_t)b1;
    cfloat* W2c = (cfloat*)(uintptr_t)W2;

    for (int op = 0; op < COUT; ++op) {
        cfloat* w1r = W1c + (size_t)op * (2 * CIN);
        float h0 = 0.f, h1 = 0.f, h2 = 0.f, h3 = 0.f;
#pragma unroll
        for (int c = 0; c < CIN; c += 4) {
            h0 = fmaf(w1r[c],     xi[c],     h0);
            h1 = fmaf(w1r[c + 1], xi[c + 1], h1);
            h2 = fmaf(w1r[c + 2], xi[c + 2], h2);
            h3 = fmaf(w1r[c + 3], xi[c + 3], h3);
        }
#pragma unroll
        for (int c = 0; c < CIN; c += 4) {
            h0 = fmaf(w1r[CIN + c],     xd[c],     h0);
            h1 = fmaf(w1r[CIN + c + 1], xd[c + 1], h1);
            h2 = fmaf(w1r[CIN + c + 2], xd[c + 2], h2);
            h3 = fmaf(w1r[CIN + c + 3], xd[c + 3], h3);
        }
        const float h = fmaxf((h0 + h1) + (h2 + h3) + b1c[op], 0.f);
        cfloat* w2r = W2c + (size_t)op * COUT;
#pragma unroll
        for (int o = 0; o < COUT; ++o)
            uacc[o] = fmaf(w2r[o], h, uacc[o]);
    }

    if (w >= 3) {
#pragma unroll
        for (int o = 0; o < COUT; ++o) Buf[w - 3][lane][o] = uacc[o];
    }
    __syncthreads();
    if (w < 3) {
#pragma unroll
        for (int o = 0; o < COUT; ++o) uacc[o] = fmaxf(uacc[o], Buf[w][lane][o]);
    }
    __syncthreads();
    if (w == 1 || w == 2) {
#pragma unroll
        for (int o = 0; o < COUT; ++o) Buf[w][lane][o] = uacc[o];
    }
    __syncthreads();
    if (w == 0) {
        float* po = out + (size_t)i * COUT;
#pragma unroll
        for (int o = 0; o < COUT; ++o) {
            float v = fmaxf(uacc[o], fmaxf(Buf[1][lane][o], Buf[2][lane][o])) + b2[o];
            if (RESID) v += resid[(size_t)i * COUT + o];
            po[o] = fmaxf(v, 0.f);
        }
    }
}

extern "C" void kernel_launch(void* const* d_in, const int* in_sizes, int n_in,
                              void* d_out, int out_size, void* d_ws, size_t ws_size,
                              hipStream_t stream) {
    const float* x    = (const float*)d_in[0];
    const float* W1_0 = (const float*)d_in[2];
    const float* b1_0 = (const float*)d_in[3];
    const float* W2_0 = (const float*)d_in[4];
    const float* b2_0 = (const float*)d_in[5];
    const float* W1_1 = (const float*)d_in[6];
    const float* b1_1 = (const float*)d_in[7];
    const float* W2_1 = (const float*)d_in[8];
    const float* b2_1 = (const float*)d_in[9];
    const float* W1_2 = (const float*)d_in[10];
    const float* b1_2 = (const float*)d_in[11];
    const float* W2_2 = (const float*)d_in[12];
    const float* b2_2 = (const float*)d_in[13];
    float* outp = (float*)d_out;

    // workspace layout (plist first for 8B alignment); max SPLN = 16
    unsigned long long* plist = (unsigned long long*)d_ws;        // 16*NPTS*6
    float* x0  = (float*)(plist + (size_t)16 * NPTS * KNB);       // 32768 x 64
    float* x1  = x0 + (size_t)NPTS * 64;                          // 32768 x 32
    float* sqb = x1 + (size_t)NPTS * 32;                          // 32768
    float* T0  = sqb + NPTS;                                      // 64 x 64
    float* T1  = T0 + 4096;                                       // 32 x 128
    float* T2  = T1 + 4096;                                       // 64 x 64
    int*   nbr = (int*)(T2 + 4096);                               // 32768 x 6

    // 1-D grids, z fastest: C=32 Q=2 SPL=16 -> 16*4*16=1024 blocks;
    //                        C=64 Q=1 SPL=8  -> 8*8*16 =1024 blocks (4 waves/SIMD)
    const int g32 = 16 * (NN / 512) * NB;
    const int g64 = 8  * (NN / 256) * NB;
    const int sgrid = NPTS / 256;
    const int pgrid = NPTS / 64;

    prep_w<<<16, 256, 0, stream>>>(W1_0, W1_1, W1_2, T0, T1, T2);

    // ---- layer 0: x (32) -> x0 (64), relu ----
    sq_kernel<32><<<sgrid, 256, 0, stream>>>(x, sqb);
    knn_scan<32, 2, 16><<<g32, 256, 0, stream>>>(x, sqb, plist);
    knn_merge<16><<<sgrid, 256, 0, stream>>>(plist, nbr);
    mlp_kernel<32, 64, false, 3><<<pgrid, 384, 0, stream>>>(x, nbr, T0, b1_0, W2_0, b2_0, nullptr, x0);

    // ---- layer 1: x0 (64) -> x1 (32), relu ----
    sq_kernel<64><<<sgrid, 256, 0, stream>>>(x0, sqb);
    knn_scan<64, 1, 8><<<g64, 256, 0, stream>>>(x0, sqb, plist);
    knn_merge<8><<<sgrid, 256, 0, stream>>>(plist, nbr);
    mlp_kernel<64, 32, false, 2><<<pgrid, 384, 0, stream>>>(x0, nbr, T1, b1_1, W2_1, b2_1, nullptr, x1);

    // ---- layer 2: x1 (32) -> out (64), +x0 residual, relu ----
    sq_kernel<32><<<sgrid, 256, 0, stream>>>(x1, sqb);
    knn_scan<32, 2, 16><<<g32, 256, 0, stream>>>(x1, sqb, plist);
    knn_merge<16><<<sgrid, 256, 0, stream>>>(plist, nbr);
    mlp_kernel<32, 64, true, 3><<<pgrid, 384, 0, stream>>>(x1, nbr, T2, b1_2, W2_2, b2_2, x0, outp);
}

// Round 10
// 750.052 us; speedup vs baseline: 1.1713x; 1.1039x over previous
//
#include <hip/hip_runtime.h>

#define NB   16
#define NN   2048
#define NPTS (NB * NN)
#define KNB  6

typedef __attribute__((ext_vector_type(8))) short short8;
typedef __attribute__((ext_vector_type(4))) float f32x4;
typedef const __attribute__((address_space(4))) float cfloat;

// ---------------- squared-norm kernel (exact fp32) ----------------
template<int C>
__global__ void sq_kernel(const float* __restrict__ x, float* __restrict__ sq) {
    int i = blockIdx.x * blockDim.x + threadIdx.x;
    if (i >= NPTS) return;
    const float4* r = (const float4*)(x + (size_t)i * C);
    float s = 0.f;
#pragma unroll
    for (int c = 0; c < C / 4; ++c) {
        float4 f = r[c];
        s += f.x * f.x + f.y * f.y + f.z * f.z + f.w * f.w;
    }
    sq[i] = s;
}

// ---------------- split-precision prep: x -> bf16 hi + bf16 lo ----------------
__device__ __forceinline__ unsigned bf16_rne(float f) {
    unsigned u = __float_as_uint(f);
    return (u + 0x7fffu + ((u >> 16) & 1u)) >> 16;
}
template<int C>
__global__ void prep_x(const float* __restrict__ x,
                       unsigned short* __restrict__ Xhi,
                       unsigned short* __restrict__ Xlo) {
    int t = blockIdx.x * 256 + threadIdx.x;
    if (t >= NPTS * C) return;
    float f = x[t];
    unsigned h = bf16_rne(f);
    float hf = __uint_as_float(h << 16);
    unsigned l = bf16_rne(f - hf);
    Xhi[t] = (unsigned short)h;
    Xlo[t] = (unsigned short)l;
}

// ---------------- weight prep: transpose the three W1s ----------------
__global__ void prep_w(const float* __restrict__ W10, const float* __restrict__ W11,
                       const float* __restrict__ W12,
                       float* __restrict__ T0, float* __restrict__ T1,
                       float* __restrict__ T2) {
    int t = blockIdx.x * 256 + threadIdx.x;
    if (t < 4096) { int o = t >> 6, c = t & 63;  T0[o * 64 + c]  = W10[c * 64 + o]; }
    if (t < 4096) { int o = t >> 7, c = t & 127; T1[o * 128 + c] = W11[c * 32 + o]; }
    if (t < 4096) { int o = t >> 6, c = t & 63;  T2[o * 64 + c]  = W12[c * 64 + o]; }
}

// branchless stable insert of (s, j) into ascending 6-list
__device__ __forceinline__ void insert6(float s, int j, float* dl, int* il) {
    float cd = s; int ci = j;
#pragma unroll
    for (int k = 0; k < 6; ++k) {
        const float od = dl[k]; const int oi = il[k];
        const bool c = cd < od;
        dl[k] = c ? cd : od;
        il[k] = c ? ci : oi;
        cd = c ? od : cd;
        ci = c ? oi : ci;
    }
}

// ---------------- MFMA kNN scan ----------------
// wave = 16 queries x 1024 candidates (split sp of the batch).
// D[j][q] = dot(cand_j, query_q) via 16x16x32 bf16 MFMA with hi/lo split
// (hi*hi + hi*lo + lo*hi): rel err ~1e-5, only used to pick a top-8-ish
// SUPERSET; exact fp32 rescore follows. C/D layout: col(lane&15)=query,
// row((lane>>4)*4+reg)=candidate. A/B frags: row/col = lane&15,
// k = (lane>>4)*8 + i. Each lane keeps top-6 of its (sp, lane>>4) sublist;
// 8 disjoint sorted sublists per query land in plist[q][8][6].
template<int C>
__global__ __launch_bounds__(256, 2)
void knn_scan(const unsigned short* __restrict__ Xhi,
              const unsigned short* __restrict__ Xlo,
              const float* __restrict__ sqv,
              unsigned long long* __restrict__ plist) {
    constexpr int KT = C / 32;
    const int w    = __builtin_amdgcn_readfirstlane(threadIdx.x >> 6);
    const int W    = blockIdx.x * 4 + w;
    const int sp   = W & 1;                 // candidate half
    const int qt   = (W >> 1) & 127;        // query tile
    const int b    = W >> 8;                // batch
    const int lane = threadIdx.x & 63;
    const int n    = lane & 15;             // query within tile (D col)
    const int g    = lane >> 4;             // row group (D rows 4g..4g+3)
    const int base = b * NN;
    const int qloc = qt * 16 + n;           // batch-local query index

    // B fragments (queries), persistent: KT tiles x {hi,lo}
    short8 bh[KT], bl[KT];
#pragma unroll
    for (int kt = 0; kt < KT; ++kt) {
        const size_t off = (size_t)(base + qloc) * C + kt * 32 + g * 8;
        bh[kt] = *(const short8*)(Xhi + off);
        bl[kt] = *(const short8*)(Xlo + off);
    }

    float dl[6]; int il[6];
#pragma unroll
    for (int k = 0; k < 6; ++k) { dl[k] = 1e30f; il[k] = 0; }

    const int jbeg = sp * (NN / 2);
    for (int jb = jbeg; jb < jbeg + NN / 2; jb += 16) {
        // A fragments (16 candidates)
        short8 ah[KT], al[KT];
#pragma unroll
        for (int kt = 0; kt < KT; ++kt) {
            const size_t off = (size_t)(base + jb + n) * C + kt * 32 + g * 8;
            ah[kt] = *(const short8*)(Xhi + off);
            al[kt] = *(const short8*)(Xlo + off);
        }
        f32x4 acc = {0.f, 0.f, 0.f, 0.f};
#pragma unroll
        for (int kt = 0; kt < KT; ++kt) {
            acc = __builtin_amdgcn_mfma_f32_16x16x32_bf16(ah[kt], bh[kt], acc, 0, 0, 0);
            acc = __builtin_amdgcn_mfma_f32_16x16x32_bf16(ah[kt], bl[kt], acc, 0, 0, 0);
            acc = __builtin_amdgcn_mfma_f32_16x16x32_bf16(al[kt], bh[kt], acc, 0, 0, 0);
        }
        const float4 sq4 = *(const float4*)(sqv + base + jb + g * 4);
#pragma unroll
        for (int r = 0; r < 4; ++r) {
            const int jloc = jb + g * 4 + r;
            float sc = fmaf(-2.f, acc[r],
                            r == 0 ? sq4.x : r == 1 ? sq4.y : r == 2 ? sq4.z : sq4.w);
            sc = (jloc == qloc) ? 1e30f : sc;     // self-exclusion (stays out)
            insert6(sc, jloc, dl, il);
        }
    }

    // write this lane's sorted sublist as packed sortable u64 keys
    unsigned long long* o = plist + (size_t)(base + qloc) * 48 + (sp * 4 + g) * 6;
#pragma unroll
    for (int k = 0; k < 6; ++k) {
        unsigned u = __float_as_uint(dl[k]);
        u ^= (u & 0x80000000u) ? 0xFFFFFFFFu : 0x80000000u;
        o[k] = ((unsigned long long)u << 11) | (unsigned)(il[k] & 2047);
    }
}

// ---------------- exact rescore: approx top-8 -> exact fp32 top-6 ----------------
// thread = query. Merge 8 sorted 6-sublists -> approx-best 8 candidates
// (superset of exact top-6 given ~1e-5 approx error), recompute their scores
// in exact fp32, pick exact top-6 with exact (dist, index) tie-break.
template<int C>
__global__ __launch_bounds__(256)
void rescore(const float* __restrict__ x, const float* __restrict__ sqv,
             const unsigned long long* __restrict__ plist, int* __restrict__ nbr) {
    const int i = blockIdx.x * 256 + threadIdx.x;
    if (i >= NPTS) return;
    const unsigned long long* pr = plist + (size_t)i * 48;

    unsigned long long best[8];
#pragma unroll
    for (int k = 0; k < 8; ++k) best[k] = ~0ull;
    for (int z = 0; z < 8; ++z) {
        const unsigned long long* p = pr + z * 6;
        for (int e = 0; e < 6; ++e) {
            unsigned long long v = p[e];
            if (v >= best[7]) break;      // sublist ascending
            best[7] = v;
#pragma unroll
            for (int k = 6; k >= 0; --k) {
                if (best[k + 1] < best[k]) {
                    unsigned long long t = best[k]; best[k] = best[k + 1]; best[k + 1] = t;
                }
            }
        }
    }

    const int base = i & ~(NN - 1);
    // query row in registers
    float4 qv[C / 4];
    const float4* qp = (const float4*)(x + (size_t)i * C);
#pragma unroll
    for (int t = 0; t < C / 4; ++t) qv[t] = qp[t];

    unsigned long long out6[6];
#pragma unroll
    for (int k = 0; k < 6; ++k) out6[k] = ~0ull;

    for (int m = 0; m < 8; ++m) {
        const int jloc = (int)(best[m] & 2047ull);
        const float4* cp = (const float4*)(x + (size_t)(base + jloc) * C);
        float d0 = 0.f, d1 = 0.f, d2 = 0.f, d3 = 0.f;
#pragma unroll
        for (int t = 0; t < C / 4; ++t) {
            float4 a = cp[t];
            d0 = fmaf(a.x, qv[t].x, d0);
            d1 = fmaf(a.y, qv[t].y, d1);
            d2 = fmaf(a.z, qv[t].z, d2);
            d3 = fmaf(a.w, qv[t].w, d3);
        }
        const float s = fmaf(-2.f, (d0 + d1) + (d2 + d3), sqv[base + jloc]);
        unsigned u = __float_as_uint(s);
        u ^= (u & 0x80000000u) ? 0xFFFFFFFFu : 0x80000000u;
        unsigned long long key = ((unsigned long long)u << 11) | (unsigned)jloc;
#pragma unroll
        for (int k = 0; k < 6; ++k) {
            const unsigned long long ok = out6[k];
            const bool c = key < ok;
            out6[k] = c ? key : ok;
            key     = c ? ok  : key;
        }
    }
#pragma unroll
    for (int k = 0; k < 6; ++k)
        nbr[i * KNB + k] = base + (int)(out6[k] & 2047ull);
}

// ---------------- edge MLP kernel ----------------
// block = 384 thr = 6 waves; lane = point; wave = neighbor. Weight streams
// via address_space(4) uniform loads (scalar pipe); 6->1 max via LDS tree.
template<int CIN, int COUT, bool RESID, int MINW>
__global__ __launch_bounds__(384, MINW)
void mlp_kernel(const float* __restrict__ xin, const int* __restrict__ nbr,
                const float* __restrict__ W1T, const float* __restrict__ b1,
                const float* __restrict__ W2,  const float* __restrict__ b2,
                const float* __restrict__ resid, float* __restrict__ out) {
    constexpr int RS = COUT + 4;
    __shared__ float Buf[3][64][RS];

    const int lane = threadIdx.x & 63;
    const int w    = __builtin_amdgcn_readfirstlane(threadIdx.x >> 6);  // 0..5
    const int i    = blockIdx.x * 64 + lane;

    float xi[CIN], xd[CIN];
    {
        const float* xp = xin + (size_t)i * CIN;
#pragma unroll
        for (int c = 0; c < CIN; c += 4) {
            float4 f = *(const float4*)(xp + c);
            xi[c] = f.x; xi[c + 1] = f.y; xi[c + 2] = f.z; xi[c + 3] = f.w;
        }
        const int j = nbr[i * KNB + w];
        const float* jp = xin + (size_t)j * CIN;
#pragma unroll
        for (int c = 0; c < CIN; c += 4) {
            float4 f = *(const float4*)(jp + c);
            xd[c]     = f.x - xi[c];     xd[c + 1] = f.y - xi[c + 1];
            xd[c + 2] = f.z - xi[c + 2]; xd[c + 3] = f.w - xi[c + 3];
        }
    }

    float uacc[COUT];
#pragma unroll
    for (int o = 0; o < COUT; ++o) uacc[o] = 0.f;

    cfloat* W1c = (cfloat*)(uintptr_t)W1T;
    cfloat* b1c = (cfloat*)(uintptr_t)b1;
    cfloat* W2c = (cfloat*)(uintptr_t)W2;

    for (int op = 0; op < COUT; ++op) {
        cfloat* w1r = W1c + (size_t)op * (2 * CIN);
        float h0 = 0.f, h1 = 0.f, h2 = 0.f, h3 = 0.f;
#pragma unroll
        for (int c = 0; c < CIN; c += 4) {
            h0 = fmaf(w1r[c],     xi[c],     h0);
            h1 = fmaf(w1r[c + 1], xi[c + 1], h1);
            h2 = fmaf(w1r[c + 2], xi[c + 2], h2);
            h3 = fmaf(w1r[c + 3], xi[c + 3], h3);
        }
#pragma unroll
        for (int c = 0; c < CIN; c += 4) {
            h0 = fmaf(w1r[CIN + c],     xd[c],     h0);
            h1 = fmaf(w1r[CIN + c + 1], xd[c + 1], h1);
            h2 = fmaf(w1r[CIN + c + 2], xd[c + 2], h2);
            h3 = fmaf(w1r[CIN + c + 3], xd[c + 3], h3);
        }
        const float h = fmaxf((h0 + h1) + (h2 + h3) + b1c[op], 0.f);
        cfloat* w2r = W2c + (size_t)op * COUT;
#pragma unroll
        for (int o = 0; o < COUT; ++o)
            uacc[o] = fmaf(w2r[o], h, uacc[o]);
    }

    if (w >= 3) {
#pragma unroll
        for (int o = 0; o < COUT; ++o) Buf[w - 3][lane][o] = uacc[o];
    }
    __syncthreads();
    if (w < 3) {
#pragma unroll
        for (int o = 0; o < COUT; ++o) uacc[o] = fmaxf(uacc[o], Buf[w][lane][o]);
    }
    __syncthreads();
    if (w == 1 || w == 2) {
#pragma unroll
        for (int o = 0; o < COUT; ++o) Buf[w][lane][o] = uacc[o];
    }
    __syncthreads();
    if (w == 0) {
        float* po = out + (size_t)i * COUT;
#pragma unroll
        for (int o = 0; o < COUT; ++o) {
            float v = fmaxf(uacc[o], fmaxf(Buf[1][lane][o], Buf[2][lane][o])) + b2[o];
            if (RESID) v += resid[(size_t)i * COUT + o];
            po[o] = fmaxf(v, 0.f);
        }
    }
}

extern "C" void kernel_launch(void* const* d_in, const int* in_sizes, int n_in,
                              void* d_out, int out_size, void* d_ws, size_t ws_size,
                              hipStream_t stream) {
    const float* x    = (const float*)d_in[0];
    const float* W1_0 = (const float*)d_in[2];
    const float* b1_0 = (const float*)d_in[3];
    const float* W2_0 = (const float*)d_in[4];
    const float* b2_0 = (const float*)d_in[5];
    const float* W1_1 = (const float*)d_in[6];
    const float* b1_1 = (const float*)d_in[7];
    const float* W2_1 = (const float*)d_in[8];
    const float* b2_1 = (const float*)d_in[9];
    const float* W1_2 = (const float*)d_in[10];
    const float* b1_2 = (const float*)d_in[11];
    const float* W2_2 = (const float*)d_in[12];
    const float* b2_2 = (const float*)d_in[13];
    float* outp = (float*)d_out;

    // workspace layout (8B-aligned first)
    unsigned long long* plist = (unsigned long long*)d_ws;        // NPTS*48 u64
    float* x0  = (float*)(plist + (size_t)NPTS * 48);             // 32768 x 64
    float* x1  = x0 + (size_t)NPTS * 64;                          // 32768 x 32
    float* sqb = x1 + (size_t)NPTS * 32;                          // 32768
    float* T0  = sqb + NPTS;                                      // 64 x 64
    float* T1  = T0 + 4096;                                       // 32 x 128
    float* T2  = T1 + 4096;                                       // 64 x 64
    unsigned short* Xhi = (unsigned short*)(T2 + 4096);           // 32768 x 64 u16
    unsigned short* Xlo = Xhi + (size_t)NPTS * 64;                // 32768 x 64 u16
    int* nbr = (int*)(Xlo + (size_t)NPTS * 64);                   // 32768 x 6

    const int sgrid  = NPTS / 256;
    const int scgrid = 1024;            // 4096 waves
    const int pgrid  = NPTS / 64;

    prep_w<<<16, 256, 0, stream>>>(W1_0, W1_1, W1_2, T0, T1, T2);

    // ---- layer 0: x (32) -> x0 (64), relu ----
    sq_kernel<32><<<sgrid, 256, 0, stream>>>(x, sqb);
    prep_x<32><<<NPTS * 32 / 256, 256, 0, stream>>>(x, Xhi, Xlo);
    knn_scan<32><<<scgrid, 256, 0, stream>>>(Xhi, Xlo, sqb, plist);
    rescore<32><<<sgrid, 256, 0, stream>>>(x, sqb, plist, nbr);
    mlp_kernel<32, 64, false, 3><<<pgrid, 384, 0, stream>>>(x, nbr, T0, b1_0, W2_0, b2_0, nullptr, x0);

    // ---- layer 1: x0 (64) -> x1 (32), relu ----
    sq_kernel<64><<<sgrid, 256, 0, stream>>>(x0, sqb);
    prep_x<64><<<NPTS * 64 / 256, 256, 0, stream>>>(x0, Xhi, Xlo);
    knn_scan<64><<<scgrid, 256, 0, stream>>>(Xhi, Xlo, sqb, plist);
    rescore<64><<<sgrid, 256, 0, stream>>>(x0, sqb, plist, nbr);
    mlp_kernel<64, 32, false, 2><<<pgrid, 384, 0, stream>>>(x0, nbr, T1, b1_1, W2_1, b2_1, nullptr, x1);

    // ---- layer 2: x1 (32) -> out (64), +x0 residual, relu ----
    sq_kernel<32><<<sgrid, 256, 0, stream>>>(x1, sqb);
    prep_x<32><<<NPTS * 32 / 256, 256, 0, stream>>>(x1, Xhi, Xlo);
    knn_scan<32><<<scgrid, 256, 0, stream>>>(Xhi, Xlo, sqb, plist);
    rescore<32><<<sgrid, 256, 0, stream>>>(x1, sqb, plist, nbr);
    mlp_kernel<32, 64, true, 3><<<pgrid, 384, 0, stream>>>(x1, nbr, T2, b1_2, W2_2, b2_2, x0, outp);
}